// Round 6
// baseline (185.603 us; speedup 1.0000x reference)
//
#include <hip/hip_runtime.h>
#include <hip/hip_bf16.h>
#include <cstdint>

#define BB 512
#define NN 512
#define FF 512
#define DD 256
#define KTOP 10
#define BM 16               // rows per tile (32 KB f32)
#define GRID 512            // one block per batch; 2 blocks/CU
#define TPB (NN/BM)         // 32 tiles per block = one batch

typedef __attribute__((ext_vector_type(8))) short bf16x8;
typedef __attribute__((ext_vector_type(4))) float f32x4;

__device__ __forceinline__ ushort f2bf(float x){
  union { __hip_bfloat16 h; ushort u; } cv;
  cv.h = __float2bfloat16(x);        // HW RNE; pairs fuse to v_cvt_pk_bf16_f32
  return cv.u;
}

__device__ __forceinline__ bf16x8 cvt8(f32x4 a, f32x4 b){
  bf16x8 r;
  r[0]=(short)f2bf(a[0]); r[1]=(short)f2bf(a[1]); r[2]=(short)f2bf(a[2]); r[3]=(short)f2bf(a[3]);
  r[4]=(short)f2bf(b[0]); r[5]=(short)f2bf(b[1]); r[6]=(short)f2bf(b[2]); r[7]=(short)f2bf(b[3]);
  return r;
}

// global f32 -> LDS, 16B/lane, linear LDS dest (wave-uniform base + lane*16)
#define GL2LDS(GSRC, LDST)                                                          \
  __builtin_amdgcn_global_load_lds(                                                 \
      (const __attribute__((address_space(1))) uint32_t*)(uintptr_t)(GSRC),         \
      (__attribute__((address_space(3))) uint32_t*)(uint32_t)(uintptr_t)(LDST),     \
      16, 0, 0)

// ---------------- single fused kernel ----------------
// Block b owns batch b: 512 rows, 32 tiles of 16 rows.
// score[m] = attn[m] * sum_e dis[m,e] * sum_k W[e,k] * drug[m,k]
// 8 waves: wave w -> e-slice s=w&3 (64 cols), k-half h=w>>2.
// LDS tile: f32 rows [16][512], chunk-XOR swizzle (chunk ^ (row&7)); source
// pre-swizzled so linear gload_lds dest + swizzled reads form the involution.
// Pipeline per tile (R4-proven): issue t+1 -> compute t -> __syncthreads -> epilogue.
// Ends with in-LDS top-10 mean by wave 0 -> out[b].
__global__ __launch_bounds__(512, 4)
void fused_kernel(const float* __restrict__ emb, const float* __restrict__ attn,
                  const float* __restrict__ W, float* __restrict__ out){
  __shared__ float Lbuf[2][BM*FF];     // 2 x 32 KB
  __shared__ float red[2][8][BM];      // 1 KB, ping-pong by t&1
  __shared__ float attn_l[NN];         // 2 KB
  __shared__ float scores_l[NN];       // 2 KB

  const int b    = blockIdx.x;
  const int tid  = threadIdx.x;
  const int w    = tid >> 6;        // wave 0..7
  const int lane = tid & 63;
  const int g    = lane >> 4;
  const int c    = lane & 15;
  const int s    = w & 3;           // e-slice
  const int h    = w >> 2;          // k-half

  // staging source offsets: issue i covers LDS 1KB region idx=w*4+i -> row r=idx>>1,
  // half hf=idx&1; lane fetches global chunk (lane ^ (r&7)) of that half.
  int offs[4];
#pragma unroll
  for (int i = 0; i < 4; ++i){
    int idx = w*4 + i;
    int r = idx >> 1, hf = idx & 1;
    offs[i] = r*FF + hf*256 + ((lane ^ (r & 7)) << 2);
  }
  const float* tbase = emb + (size_t)b * (NN*FF);

  // issue tile 0 staging first so it overlaps the W/attn prologue loads
#pragma unroll
  for (int i = 0; i < 4; ++i)
    GL2LDS(tbase + offs[i], &Lbuf[0][(w*4 + i)*256]);

  // attn for this batch -> LDS (synced by first barrier)
  attn_l[tid] = attn[b*NN + tid];

  // W B-fragments from f32 (L2/L3-cached): B[k][e] = W[e][k];
  // e = s*64+eb*16+c, k = h*128+kb*32+g*8..+8   (64 VGPR)
  bf16x8 Wf[4][4];
#pragma unroll
  for (int eb = 0; eb < 4; ++eb)
#pragma unroll
    for (int kb = 0; kb < 4; ++kb){
      const float* wp = W + (s*64 + eb*16 + c)*DD + h*128 + kb*32 + g*8;
      f32x4 q0 = *reinterpret_cast<const f32x4*>(wp);
      f32x4 q1 = *reinterpret_cast<const f32x4*>(wp + 4);
      Wf[eb][kb] = cvt8(q0, q1);
    }

  __syncthreads();   // tile 0 resident (vmcnt drain), attn_l visible

  for (int t = 0; t < TPB; ++t){
    // issue next tile's loads; they stream during compute, drain at the barrier
    if (t + 1 < TPB){
      const float* nb = tbase + (size_t)(t+1) * (BM*FF);
#pragma unroll
      for (int i = 0; i < 4; ++i)
        GL2LDS(nb + offs[i], &Lbuf[(t+1) & 1][(w*4 + i)*256]);
    }

    // ---- compute tile t from Lbuf[t&1] ----
    const f32x4* Lv = (const f32x4*)&Lbuf[t & 1][0];
    const int rb = c*128;             // row base in float4 units (row = c)
    const int x  = c & 7;
    bf16x8 af[4];
#pragma unroll
    for (int kb = 0; kb < 4; ++kb){   // drug chunks, swizzled lookup, cvt to bf16
      int ch0 = h*32 + kb*8 + g*2;
      f32x4 q0 = Lv[rb + ((ch0    ) ^ x)];
      f32x4 q1 = Lv[rb + ((ch0 + 1) ^ x)];
      af[kb] = cvt8(q0, q1);
    }
    float rs0=0.f, rs1=0.f, rs2=0.f, rs3=0.f;
#pragma unroll
    for (int eb = 0; eb < 4; ++eb){
      f32x4 acc = {0.f, 0.f, 0.f, 0.f};
#pragma unroll
      for (int kb = 0; kb < 4; ++kb)
        acc = __builtin_amdgcn_mfma_f32_16x16x32_bf16(af[kb], Wf[eb][kb], acc, 0, 0, 0);
      // C[g*4+j][s*64+eb*16+c] in acc[j]; dis (f32) from swizzled LDS (<=2-way, free)
      const int sb = 64 + s*16 + eb*4 + (c >> 2);
      const int e3 = c & 3;
#pragma unroll
      for (int j = 0; j < 4; ++j){
        const int row = g*4 + j;
        const int fi  = row*FF + ((sb ^ (row & 7)) << 2) + e3;
        float d = Lbuf[t & 1][fi];
        if      (j == 0) rs0 += acc[0]*d;
        else if (j == 1) rs1 += acc[1]*d;
        else if (j == 2) rs2 += acc[2]*d;
        else             rs3 += acc[3]*d;
      }
    }
    rs0 += __shfl_xor(rs0,1); rs0 += __shfl_xor(rs0,2); rs0 += __shfl_xor(rs0,4); rs0 += __shfl_xor(rs0,8);
    rs1 += __shfl_xor(rs1,1); rs1 += __shfl_xor(rs1,2); rs1 += __shfl_xor(rs1,4); rs1 += __shfl_xor(rs1,8);
    rs2 += __shfl_xor(rs2,1); rs2 += __shfl_xor(rs2,2); rs2 += __shfl_xor(rs2,4); rs2 += __shfl_xor(rs2,8);
    rs3 += __shfl_xor(rs3,1); rs3 += __shfl_xor(rs3,2); rs3 += __shfl_xor(rs3,4); rs3 += __shfl_xor(rs3,8);
    if (c == 0){
      red[t&1][w][g*4 + 0] = rs0;
      red[t&1][w][g*4 + 1] = rs1;
      red[t&1][w][g*4 + 2] = rs2;
      red[t&1][w][g*4 + 3] = rs3;
    }

    __syncthreads();   // tile t+1 resident; red[t&1] visible

    if (tid < BM){     // epilogue: score -> LDS (no global round-trip)
      float sum = red[t&1][0][tid] + red[t&1][1][tid] + red[t&1][2][tid] + red[t&1][3][tid]
                + red[t&1][4][tid] + red[t&1][5][tid] + red[t&1][6][tid] + red[t&1][7][tid];
      scores_l[t*BM + tid] = attn_l[t*BM + tid] * sum;
    }
    // safe without extra barrier: next tile writes red[(t+1)&1]; red[t&1] is not
    // rewritten until after the NEXT __syncthreads (program order protects the read).
  }

  __syncthreads();     // last epilogue's scores_l writes visible

  // ---- in-block top-K mean over scores_l[512], wave 0 only ----
  if (w == 0){
    float v0,v1,v2,v3,v4,v5,v6,v7;
    v0=scores_l[lane];     v1=scores_l[64+lane];  v2=scores_l[128+lane]; v3=scores_l[192+lane];
    v4=scores_l[256+lane]; v5=scores_l[320+lane]; v6=scores_l[384+lane]; v7=scores_l[448+lane];
    float total = 0.f;
    for (int it = 0; it < KTOP; ++it){
      float m = v0; int mj = 0;
      if (v1>m){m=v1;mj=1;} if (v2>m){m=v2;mj=2;} if (v3>m){m=v3;mj=3;}
      if (v4>m){m=v4;mj=4;} if (v5>m){m=v5;mj=5;} if (v6>m){m=v6;mj=6;}
      if (v7>m){m=v7;mj=7;}
      float bm = m; int bl = lane;
#pragma unroll
      for (int off = 32; off; off >>= 1){
        float om = __shfl_xor(bm, off);
        int   ol = __shfl_xor(bl, off);
        if (om > bm || (om == bm && ol < bl)){ bm = om; bl = ol; }
      }
      total += bm;
      if (lane == bl){
        if (mj==0) v0=-3.0e38f; else if (mj==1) v1=-3.0e38f;
        else if (mj==2) v2=-3.0e38f; else if (mj==3) v3=-3.0e38f;
        else if (mj==4) v4=-3.0e38f; else if (mj==5) v5=-3.0e38f;
        else if (mj==6) v6=-3.0e38f; else v7=-3.0e38f;
      }
    }
    if (lane == 0) out[b] = total * (1.0f / KTOP);
  }
}

extern "C" void kernel_launch(void* const* d_in, const int* in_sizes, int n_in,
                              void* d_out, int out_size, void* d_ws, size_t ws_size,
                              hipStream_t stream){
  const float* emb  = (const float*)d_in[0];   // (B,N,F) f32
  const float* attn = (const float*)d_in[1];   // (B,N,1) f32
  const float* W    = (const float*)d_in[2];   // (D,D) f32
  float* out = (float*)d_out;                  // (B,1) f32

  fused_kernel<<<GRID, 512, 0, stream>>>(emb, attn, W, out);
}

// Round 7
// 108.002 us; speedup vs baseline: 1.7185x; 1.7185x over previous
//
#include <hip/hip_runtime.h>
#include <hip/hip_bf16.h>
#include <cstdint>

#define BB 512
#define NN 512
#define FF 512
#define DD 256
#define KTOP 10
#define BM 32               // rows per tile (64 KB f32)
#define GRID 256            // 1 block/CU; each block owns 1024 rows = 2 batches
#define TPB 32              // tiles per block

typedef __attribute__((ext_vector_type(8))) short bf16x8;
typedef __attribute__((ext_vector_type(4))) float f32x4;

__device__ __forceinline__ ushort f2bf(float x){
  union { __hip_bfloat16 h; ushort u; } cv;
  cv.h = __float2bfloat16(x);        // HW RNE; pairs fuse to v_cvt_pk_bf16_f32
  return cv.u;
}

__device__ __forceinline__ bf16x8 cvt8(f32x4 a, f32x4 b){
  bf16x8 r;
  r[0]=(short)f2bf(a[0]); r[1]=(short)f2bf(a[1]); r[2]=(short)f2bf(a[2]); r[3]=(short)f2bf(a[3]);
  r[4]=(short)f2bf(b[0]); r[5]=(short)f2bf(b[1]); r[6]=(short)f2bf(b[2]); r[7]=(short)f2bf(b[3]);
  return r;
}

// global f32 -> LDS, 16B/lane, linear LDS dest (wave-uniform base + lane*16)
#define GL2LDS(GSRC, LDST)                                                          \
  __builtin_amdgcn_global_load_lds(                                                 \
      (const __attribute__((address_space(1))) uint32_t*)(uintptr_t)(GSRC),         \
      (__attribute__((address_space(3))) uint32_t*)(uint32_t)(uintptr_t)(LDST),     \
      16, 0, 0)

// ---------------- single fused kernel (R4 pipeline + fused W-convert + fused topk) ----
// Block b owns rows [b*1024, b*1024+1024) = batches 2b, 2b+1; 32 tiles of 32 rows.
// score[m] = attn[m] * sum_e dis[m,e] * sum_k W[e,k] * drug[m,k]
// 8 waves: wave w -> e-slice s=w&3 (64 cols), k-half h=w>>2.
// LDS tile: f32 rows [32][512], chunk-XOR swizzle (chunk ^ (row&7)); source
// pre-swizzled so linear gload_lds dest + swizzled reads form the involution.
// Per tile: issue t+1 -> compute t -> __syncthreads (drain = productive stream wait)
// -> epilogue to scores_l. Ends with two parallel in-wave top-10 means.
__global__ __launch_bounds__(512, 2)
void fused_kernel(const float* __restrict__ emb, const float* __restrict__ attn,
                  const float* __restrict__ W, float* __restrict__ out){
  __shared__ float Lbuf[2][BM*FF];     // 2 x 64 KB
  __shared__ float red[2][8][BM];      // 2 KB, ping-pong by buffer parity
  __shared__ float attn_l[TPB*BM];     // 4 KB (1024 rows)
  __shared__ float scores_l[TPB*BM];   // 4 KB

  const int tid  = threadIdx.x;
  const int w    = tid >> 6;        // wave 0..7
  const int lane = tid & 63;
  const int g    = lane >> 4;
  const int c    = lane & 15;
  const int s    = w & 3;           // e-slice
  const int h    = w >> 2;          // k-half

  // staging source offsets: issue i covers LDS 1KB region idx=w*8+i -> row r=idx>>1,
  // half hf=idx&1; lane fetches global chunk (lane ^ (r&7)) of that half.
  int offs[8];
#pragma unroll
  for (int i = 0; i < 8; ++i){
    int idx = w*8 + i;
    int r = idx >> 1, hf = idx & 1;
    offs[i] = r*FF + hf*256 + ((lane ^ (r & 7)) << 2);
  }
  const float* tbase = emb + (size_t)blockIdx.x * (TPB*BM*FF);

  // issue tile 0 staging FIRST so W/attn prologue loads stream under it
#pragma unroll
  for (int i = 0; i < 8; ++i)
    GL2LDS(tbase + offs[i], &Lbuf[0][(w*8 + i)*256]);

  // attn for this block's 1024 rows -> LDS (visible after first barrier)
  attn_l[tid]       = attn[blockIdx.x*(TPB*BM) + tid];
  attn_l[tid + 512] = attn[blockIdx.x*(TPB*BM) + 512 + tid];

  // W B-fragments from f32 (L2-resident after first touches): B[k][e] = W[e][k];
  // e = s*64+eb*16+c, k = h*128+kb*32+g*8..+8   (64 VGPR)
  bf16x8 Wf[4][4];
#pragma unroll
  for (int eb = 0; eb < 4; ++eb)
#pragma unroll
    for (int kb = 0; kb < 4; ++kb){
      const float* wp = W + (s*64 + eb*16 + c)*DD + h*128 + kb*32 + g*8;
      f32x4 q0 = *reinterpret_cast<const f32x4*>(wp);
      f32x4 q1 = *reinterpret_cast<const f32x4*>(wp + 4);
      Wf[eb][kb] = cvt8(q0, q1);
    }

  __syncthreads();   // tile 0 resident (vmcnt drain); attn_l visible

  int cur = 0;
  for (int t = 0; t < TPB; ++t){
    // issue next tile's loads; they stream during compute, drain at the barrier
    if (t + 1 < TPB){
      const float* nb = tbase + (size_t)(t+1) * (BM*FF);
#pragma unroll
      for (int i = 0; i < 8; ++i)
        GL2LDS(nb + offs[i], &Lbuf[cur ^ 1][(w*8 + i)*256]);
    }

    // ---- compute tile t from Lbuf[cur] ----
    const f32x4* Lv = (const f32x4*)&Lbuf[cur][0];
#pragma unroll
    for (int mb = 0; mb < 2; ++mb){
      const int m0 = mb*16;
      const int rb = (m0 + c)*128;      // row base in float4 units
      const int x  = c & 7;             // (m0+c)&7 == c&7 since m0 % 16 == 0
      bf16x8 af[4];
#pragma unroll
      for (int kb = 0; kb < 4; ++kb){   // drug chunks, swizzled lookup, cvt to bf16
        int ch0 = h*32 + kb*8 + g*2;
        f32x4 q0 = Lv[rb + ((ch0    ) ^ x)];
        f32x4 q1 = Lv[rb + ((ch0 + 1) ^ x)];
        af[kb] = cvt8(q0, q1);
      }
      float rs0=0.f, rs1=0.f, rs2=0.f, rs3=0.f;
#pragma unroll
      for (int eb = 0; eb < 4; ++eb){
        f32x4 acc = {0.f, 0.f, 0.f, 0.f};
#pragma unroll
        for (int kb = 0; kb < 4; ++kb)
          acc = __builtin_amdgcn_mfma_f32_16x16x32_bf16(af[kb], Wf[eb][kb], acc, 0, 0, 0);
        // C[m0+g*4+j][s*64+eb*16+c] in acc[j]; dis (f32) from swizzled LDS (<=2-way, free)
        const int sb = 64 + s*16 + eb*4 + (c >> 2);
        const int e3 = c & 3;
#pragma unroll
        for (int j = 0; j < 4; ++j){
          const int row = m0 + g*4 + j;
          const int fi  = row*FF + ((sb ^ (row & 7)) << 2) + e3;
          float d = Lbuf[cur][fi];
          if      (j == 0) rs0 += acc[0]*d;
          else if (j == 1) rs1 += acc[1]*d;
          else if (j == 2) rs2 += acc[2]*d;
          else             rs3 += acc[3]*d;
        }
      }
      rs0 += __shfl_xor(rs0,1); rs0 += __shfl_xor(rs0,2); rs0 += __shfl_xor(rs0,4); rs0 += __shfl_xor(rs0,8);
      rs1 += __shfl_xor(rs1,1); rs1 += __shfl_xor(rs1,2); rs1 += __shfl_xor(rs1,4); rs1 += __shfl_xor(rs1,8);
      rs2 += __shfl_xor(rs2,1); rs2 += __shfl_xor(rs2,2); rs2 += __shfl_xor(rs2,4); rs2 += __shfl_xor(rs2,8);
      rs3 += __shfl_xor(rs3,1); rs3 += __shfl_xor(rs3,2); rs3 += __shfl_xor(rs3,4); rs3 += __shfl_xor(rs3,8);
      if (c == 0){
        red[cur][w][m0 + g*4 + 0] = rs0;
        red[cur][w][m0 + g*4 + 1] = rs1;
        red[cur][w][m0 + g*4 + 2] = rs2;
        red[cur][w][m0 + g*4 + 3] = rs3;
      }
    }

    __syncthreads();   // tile t+1 resident; red[cur] visible

    if (tid < BM){     // epilogue: score -> LDS (no global round-trip)
      float sum = red[cur][0][tid] + red[cur][1][tid] + red[cur][2][tid] + red[cur][3][tid]
                + red[cur][4][tid] + red[cur][5][tid] + red[cur][6][tid] + red[cur][7][tid];
      scores_l[t*BM + tid] = attn_l[t*BM + tid] * sum;
    }
    // next tile writes red[cur^1]; red[cur] not rewritten until after the NEXT
    // __syncthreads, so this read is race-free (R4-proven scheme).
    cur ^= 1;
  }

  __syncthreads();     // last epilogue's scores_l writes visible

  // ---- two parallel in-wave top-K means: wave 0 -> batch 2b, wave 1 -> batch 2b+1 ----
  if (w < 2){
    const float* sc = scores_l + w*NN;
    float v0,v1,v2,v3,v4,v5,v6,v7;
    v0=sc[lane];     v1=sc[64+lane];  v2=sc[128+lane]; v3=sc[192+lane];
    v4=sc[256+lane]; v5=sc[320+lane]; v6=sc[384+lane]; v7=sc[448+lane];
    float total = 0.f;
    for (int it = 0; it < KTOP; ++it){
      float m = v0; int mj = 0;
      if (v1>m){m=v1;mj=1;} if (v2>m){m=v2;mj=2;} if (v3>m){m=v3;mj=3;}
      if (v4>m){m=v4;mj=4;} if (v5>m){m=v5;mj=5;} if (v6>m){m=v6;mj=6;}
      if (v7>m){m=v7;mj=7;}
      float bm = m; int bl = lane;
#pragma unroll
      for (int off = 32; off; off >>= 1){
        float om = __shfl_xor(bm, off);
        int   ol = __shfl_xor(bl, off);
        if (om > bm || (om == bm && ol < bl)){ bm = om; bl = ol; }
      }
      total += bm;
      if (lane == bl){
        if (mj==0) v0=-3.0e38f; else if (mj==1) v1=-3.0e38f;
        else if (mj==2) v2=-3.0e38f; else if (mj==3) v3=-3.0e38f;
        else if (mj==4) v4=-3.0e38f; else if (mj==5) v5=-3.0e38f;
        else if (mj==6) v6=-3.0e38f; else v7=-3.0e38f;
      }
    }
    if (lane == 0) out[blockIdx.x*2 + w] = total * (1.0f / KTOP);
  }
}

extern "C" void kernel_launch(void* const* d_in, const int* in_sizes, int n_in,
                              void* d_out, int out_size, void* d_ws, size_t ws_size,
                              hipStream_t stream){
  const float* emb  = (const float*)d_in[0];   // (B,N,F) f32
  const float* attn = (const float*)d_in[1];   // (B,N,1) f32
  const float* W    = (const float*)d_in[2];   // (D,D) f32
  float* out = (float*)d_out;                  // (B,1) f32

  fused_kernel<<<GRID, 512, 0, stream>>>(emb, attn, W, out);
}

// Round 8
// 106.813 us; speedup vs baseline: 1.7376x; 1.0111x over previous
//
#include <hip/hip_runtime.h>
#include <hip/hip_bf16.h>
#include <cstdint>

#define BB 512
#define NN 512
#define FF 512
#define DD 256
#define KTOP 10
#define BM 32               // rows per tile (64 KB f32)
#define GRID 256            // 1 block/CU; each block owns 1024 rows = 2 batches
#define TPB 32              // tiles per block (even -> clean x2 unroll)

typedef __attribute__((ext_vector_type(8))) short bf16x8;
typedef __attribute__((ext_vector_type(4))) float f32x4;

__device__ __forceinline__ ushort f2bf(float x){
  union { __hip_bfloat16 h; ushort u; } cv;
  cv.h = __float2bfloat16(x);        // HW RNE; pairs fuse to v_cvt_pk_bf16_f32
  return cv.u;
}

__device__ __forceinline__ bf16x8 cvt8(f32x4 a, f32x4 b){
  bf16x8 r;
  r[0]=(short)f2bf(a[0]); r[1]=(short)f2bf(a[1]); r[2]=(short)f2bf(a[2]); r[3]=(short)f2bf(a[3]);
  r[4]=(short)f2bf(b[0]); r[5]=(short)f2bf(b[1]); r[6]=(short)f2bf(b[2]); r[7]=(short)f2bf(b[3]);
  return r;
}

// global f32 -> LDS, 16B/lane, linear LDS dest (wave-uniform base + lane*16)
#define GL2LDS(GSRC, LDST)                                                          \
  __builtin_amdgcn_global_load_lds(                                                 \
      (const __attribute__((address_space(1))) uint32_t*)(uintptr_t)(GSRC),         \
      (__attribute__((address_space(3))) uint32_t*)(uint32_t)(uintptr_t)(LDST),     \
      16, 0, 0)

// ---------------- single fused kernel ----------------
// Block b owns rows [b*1024, b*1024+1024) = batches 2b, 2b+1; 32 tiles of 32 rows.
// score[m] = attn[m] * sum_e dis[m,e] * sum_k W[e,k] * drug[m,k]
// 8 waves: wave w -> e-slice s=w&3 (64 cols), k-half h=w>>2.
// LDS tile: f32 rows [32][512], chunk-XOR swizzle (chunk ^ (row&7)); source
// pre-swizzled so linear gload_lds dest + swizzled reads form the involution.
// KEY CHANGE vs R7: two STATIC __shared__ buffers + x2-unrolled tile loop, so the
// compiler can prove the staged buffer and the computed buffer never alias and
// does NOT insert a vmcnt(0) before the compute-phase ds_reads.
__global__ __launch_bounds__(512, 2)
void fused_kernel(const float* __restrict__ emb, const float* __restrict__ attn,
                  const float* __restrict__ W, float* __restrict__ out){
  __shared__ float LA[BM*FF];          // 64 KB
  __shared__ float LB[BM*FF];          // 64 KB
  __shared__ float red[2][8][BM];      // 2 KB, parity by tile index (compile-time)
  __shared__ float attn_l[TPB*BM];     // 4 KB (1024 rows)
  __shared__ float scores_l[TPB*BM];   // 4 KB

  const int tid  = threadIdx.x;
  const int w    = tid >> 6;        // wave 0..7
  const int lane = tid & 63;
  const int g    = lane >> 4;
  const int c    = lane & 15;
  const int s    = w & 3;           // e-slice
  const int h    = w >> 2;          // k-half

  // staging source offsets: issue i covers LDS 1KB region idx=w*8+i -> row r=idx>>1,
  // half hf=idx&1; lane fetches global chunk (lane ^ (r&7)) of that half.
  int offs[8];
#pragma unroll
  for (int i = 0; i < 8; ++i){
    int idx = w*8 + i;
    int r = idx >> 1, hf = idx & 1;
    offs[i] = r*FF + hf*256 + ((lane ^ (r & 7)) << 2);
  }
  const float* tbase = emb + (size_t)blockIdx.x * (TPB*BM*FF);

  // issue tile 0 staging FIRST so W/attn prologue loads stream under it
#pragma unroll
  for (int i = 0; i < 8; ++i)
    GL2LDS(tbase + offs[i], &LA[(w*8 + i)*256]);

  // attn for this block's 1024 rows -> LDS (visible after first barrier)
  attn_l[tid]       = attn[blockIdx.x*(TPB*BM) + tid];
  attn_l[tid + 512] = attn[blockIdx.x*(TPB*BM) + 512 + tid];

  // W B-fragments from f32 (L2-resident): B[k][e] = W[e][k];
  // e = s*64+eb*16+c, k = h*128+kb*32+g*8..+8   (64 VGPR)
  bf16x8 Wf[4][4];
#pragma unroll
  for (int eb = 0; eb < 4; ++eb)
#pragma unroll
    for (int kb = 0; kb < 4; ++kb){
      const float* wp = W + (s*64 + eb*16 + c)*DD + h*128 + kb*32 + g*8;
      f32x4 q0 = *reinterpret_cast<const f32x4*>(wp);
      f32x4 q1 = *reinterpret_cast<const f32x4*>(wp + 4);
      Wf[eb][kb] = cvt8(q0, q1);
    }

  __syncthreads();   // tile 0 resident (vmcnt drain); attn_l visible

  // ---- tile body: reads RD (resident), stages tile T+1 into WR, PAR = T&1 ----
#define TILE_BODY(T, RD, WR, PAR)                                                   \
  do {                                                                              \
    if ((T) + 1 < TPB){                                                             \
      const float* nb_ = tbase + (size_t)((T)+1) * (BM*FF);                         \
      _Pragma("unroll")                                                             \
      for (int i = 0; i < 8; ++i)                                                   \
        GL2LDS(nb_ + offs[i], &WR[(w*8 + i)*256]);                                  \
    }                                                                               \
    const f32x4* Lv = (const f32x4*)&RD[0];                                         \
    _Pragma("unroll")                                                               \
    for (int mb = 0; mb < 2; ++mb){                                                 \
      const int m0 = mb*16;                                                         \
      const int rb = (m0 + c)*128;                                                  \
      const int x  = c & 7;                                                         \
      bf16x8 af[4];                                                                 \
      _Pragma("unroll")                                                             \
      for (int kb = 0; kb < 4; ++kb){                                               \
        int ch0 = h*32 + kb*8 + g*2;                                                \
        f32x4 q0 = Lv[rb + ((ch0    ) ^ x)];                                        \
        f32x4 q1 = Lv[rb + ((ch0 + 1) ^ x)];                                        \
        af[kb] = cvt8(q0, q1);                                                      \
      }                                                                             \
      float rs0=0.f, rs1=0.f, rs2=0.f, rs3=0.f;                                     \
      _Pragma("unroll")                                                             \
      for (int eb = 0; eb < 4; ++eb){                                               \
        f32x4 acc = {0.f, 0.f, 0.f, 0.f};                                           \
        _Pragma("unroll")                                                           \
        for (int kb = 0; kb < 4; ++kb)                                              \
          acc = __builtin_amdgcn_mfma_f32_16x16x32_bf16(af[kb], Wf[eb][kb], acc, 0, 0, 0); \
        const int sb = 64 + s*16 + eb*4 + (c >> 2);                                 \
        const int e3 = c & 3;                                                       \
        _Pragma("unroll")                                                           \
        for (int j = 0; j < 4; ++j){                                                \
          const int row = m0 + g*4 + j;                                             \
          const int fi  = row*FF + ((sb ^ (row & 7)) << 2) + e3;                    \
          float d = RD[fi];                                                         \
          if      (j == 0) rs0 += acc[0]*d;                                         \
          else if (j == 1) rs1 += acc[1]*d;                                         \
          else if (j == 2) rs2 += acc[2]*d;                                         \
          else             rs3 += acc[3]*d;                                         \
        }                                                                           \
      }                                                                             \
      rs0 += __shfl_xor(rs0,1); rs0 += __shfl_xor(rs0,2); rs0 += __shfl_xor(rs0,4); rs0 += __shfl_xor(rs0,8); \
      rs1 += __shfl_xor(rs1,1); rs1 += __shfl_xor(rs1,2); rs1 += __shfl_xor(rs1,4); rs1 += __shfl_xor(rs1,8); \
      rs2 += __shfl_xor(rs2,1); rs2 += __shfl_xor(rs2,2); rs2 += __shfl_xor(rs2,4); rs2 += __shfl_xor(rs2,8); \
      rs3 += __shfl_xor(rs3,1); rs3 += __shfl_xor(rs3,2); rs3 += __shfl_xor(rs3,4); rs3 += __shfl_xor(rs3,8); \
      if (c == 0){                                                                  \
        red[PAR][w][m0 + g*4 + 0] = rs0;                                            \
        red[PAR][w][m0 + g*4 + 1] = rs1;                                            \
        red[PAR][w][m0 + g*4 + 2] = rs2;                                            \
        red[PAR][w][m0 + g*4 + 3] = rs3;                                            \
      }                                                                             \
    }                                                                               \
    __syncthreads();   /* tile T+1 resident; red[PAR] visible */                    \
    if (tid < BM){                                                                  \
      float sum = red[PAR][0][tid] + red[PAR][1][tid] + red[PAR][2][tid] + red[PAR][3][tid] \
                + red[PAR][4][tid] + red[PAR][5][tid] + red[PAR][6][tid] + red[PAR][7][tid]; \
      scores_l[(T)*BM + tid] = attn_l[(T)*BM + tid] * sum;                          \
    }                                                                               \
  } while(0)

  for (int t = 0; t < TPB; t += 2){
    TILE_BODY(t,     LA, LB, 0);
    TILE_BODY(t + 1, LB, LA, 1);
  }
#undef TILE_BODY

  __syncthreads();     // last epilogue's scores_l writes visible

  // ---- two parallel in-wave top-K means: wave 0 -> batch 2b, wave 1 -> batch 2b+1 ----
  if (w < 2){
    const float* sc = scores_l + w*NN;
    float v0,v1,v2,v3,v4,v5,v6,v7;
    v0=sc[lane];     v1=sc[64+lane];  v2=sc[128+lane]; v3=sc[192+lane];
    v4=sc[256+lane]; v5=sc[320+lane]; v6=sc[384+lane]; v7=sc[448+lane];
    float total = 0.f;
    for (int it = 0; it < KTOP; ++it){
      float m = v0; int mj = 0;
      if (v1>m){m=v1;mj=1;} if (v2>m){m=v2;mj=2;} if (v3>m){m=v3;mj=3;}
      if (v4>m){m=v4;mj=4;} if (v5>m){m=v5;mj=5;} if (v6>m){m=v6;mj=6;}
      if (v7>m){m=v7;mj=7;}
      float bm = m; int bl = lane;
#pragma unroll
      for (int off = 32; off; off >>= 1){
        float om = __shfl_xor(bm, off);
        int   ol = __shfl_xor(bl, off);
        if (om > bm || (om == bm && ol < bl)){ bm = om; bl = ol; }
      }
      total += bm;
      if (lane == bl){
        if (mj==0) v0=-3.0e38f; else if (mj==1) v1=-3.0e38f;
        else if (mj==2) v2=-3.0e38f; else if (mj==3) v3=-3.0e38f;
        else if (mj==4) v4=-3.0e38f; else if (mj==5) v5=-3.0e38f;
        else if (mj==6) v6=-3.0e38f; else v7=-3.0e38f;
      }
    }
    if (lane == 0) out[blockIdx.x*2 + w] = total * (1.0f / KTOP);
  }
}

extern "C" void kernel_launch(void* const* d_in, const int* in_sizes, int n_in,
                              void* d_out, int out_size, void* d_ws, size_t ws_size,
                              hipStream_t stream){
  const float* emb  = (const float*)d_in[0];   // (B,N,F) f32
  const float* attn = (const float*)d_in[1];   // (B,N,1) f32
  const float* W    = (const float*)d_in[2];   // (D,D) f32
  float* out = (float*)d_out;                  // (B,1) f32

  fused_kernel<<<GRID, 512, 0, stream>>>(emb, attn, W, out);
}